// Round 3
// baseline (330.209 us; speedup 1.0000x reference)
//
#include <hip/hip_runtime.h>
#include <hip/hip_bf16.h>
#include <math.h>

// Problem constants
#define NN 32768
#define CC 512
#define AA 64
#define CIN 1024
#define EPSV 1e-7f

// All inputs/outputs are FLOAT32 (reference dtype).
//
// Workspace layout (floats):
//   [0,576)      query dots (atomic-accumulated, pre-bias)
//   [576,1088)   erase dots (pre-bias)
//   [1088,1600)  conth = W_content_hidden @ h
//   [1600,2112)  contx = W_content_input @ x   (direct store)
//   [2112,2128)  scalars: 2112 beta, 2113 gamma, 2114 alpha, 2115 qnorm,
//                         2116 mx, 2117 invZ, 2118 S2
//   [2128,2704)  qfull[576] = query + b_query
//   [2704,35472)   s[32768] (pre-softmax logits)
//   [35472,559760) part_m[1024][512]  (elem-major partials: e*512+blk)
//   [559760,567952) part_a[64][128]
// Total 567952 floats = 2.27 MB

#define QOFF 2128
#define SOFF 2704
#define PMOFF 35472
#define PAOFF 559760

// ---------------- K1: all GEMVs + scalar dots, row-blocked ----------------
// grid 1688 blocks x 256 thr:
//   b<1600 : big GEMV (rows [0,1600) over Wq/Wer/Wch). rg=b>>3 (8 rows),
//            chunk=b&7 (4096 cols). h chunk staged in LDS, shared by 8 rows.
//            Partial dot -> atomicAdd(ws[row]).
//   b<1664 : Wci rows (8 per block, full 1024 cols) -> direct store.
//   b<1688 : 3 scalar dots x 8 chunks -> atomicAdd(ws[2112+sd]).
__global__ __launch_bounds__(256) void k1_gemv(
    const float* __restrict__ h, const float* __restrict__ x,
    const float* __restrict__ Wq, const float* __restrict__ Wer,
    const float* __restrict__ Wch, const float* __restrict__ Wci,
    const float* __restrict__ ush, const float* __restrict__ ulr,
    const float* __restrict__ uca, float* __restrict__ ws)
{
    const int b = blockIdx.x, tid = threadIdx.x;
    const int wave = tid >> 6, lane = tid & 63;
    __shared__ float hs[4096];
    __shared__ float red[4][8];

    if (b < 1600) {
        const int rg = b >> 3, chunk = b & 7;
        const float4* h4 = reinterpret_cast<const float4*>(h) + chunk * 1024;
        float4* hs4 = reinterpret_cast<float4*>(hs);
        #pragma unroll
        for (int k = 0; k < 4; ++k) hs4[k * 256 + tid] = h4[k * 256 + tid];
        __syncthreads();
        const int r0 = rg * 8;
        const float* mat; int base;
        if (r0 < 576)       { mat = Wq;  base = 0; }
        else if (r0 < 1088) { mat = Wer; base = 576; }
        else                { mat = Wch; base = 1088; }
        const float4* m4 = reinterpret_cast<const float4*>(
            mat + (size_t)(r0 - base) * NN + chunk * 4096);
        const int rs = NN / 4; // row stride in float4
        float acc[8] = {0,0,0,0,0,0,0,0};
        #pragma unroll
        for (int it = 0; it < 4; ++it) {
            float4 hb = hs4[it * 256 + tid];
            #pragma unroll
            for (int r = 0; r < 8; ++r) {
                float4 a = m4[(size_t)r * rs + it * 256 + tid];
                acc[r] += a.x * hb.x + a.y * hb.y + a.z * hb.z + a.w * hb.w;
            }
        }
        #pragma unroll
        for (int r = 0; r < 8; ++r) {
            #pragma unroll
            for (int off = 32; off >= 1; off >>= 1)
                acc[r] += __shfl_xor(acc[r], off);
        }
        if (lane == 0) {
            #pragma unroll
            for (int r = 0; r < 8; ++r) red[wave][r] = acc[r];
        }
        __syncthreads();
        if (tid < 8) {
            float v = red[0][tid] + red[1][tid] + red[2][tid] + red[3][tid];
            atomicAdd(ws + r0 + tid, v);
        }
    } else if (b < 1664) {
        const int rg = b - 1600; // 8 rows of Wci each
        float4 xv = reinterpret_cast<const float4*>(x)[tid];
        const float4* m4 = reinterpret_cast<const float4*>(
            Wci + (size_t)rg * 8 * CIN);
        float acc[8];
        #pragma unroll
        for (int r = 0; r < 8; ++r) {
            float4 a = m4[r * 256 + tid];
            acc[r] = a.x * xv.x + a.y * xv.y + a.z * xv.z + a.w * xv.w;
        }
        #pragma unroll
        for (int r = 0; r < 8; ++r) {
            #pragma unroll
            for (int off = 32; off >= 1; off >>= 1)
                acc[r] += __shfl_xor(acc[r], off);
        }
        if (lane == 0) {
            #pragma unroll
            for (int r = 0; r < 8; ++r) red[wave][r] = acc[r];
        }
        __syncthreads();
        if (tid < 8) {
            float v = red[0][tid] + red[1][tid] + red[2][tid] + red[3][tid];
            ws[1600 + rg * 8 + tid] = v;
        }
    } else {
        const int t = b - 1664, sd = t >> 3, chunk = t & 7;
        const float* vec = (sd == 0) ? ush : (sd == 1) ? ulr : uca;
        const float4* v4 = reinterpret_cast<const float4*>(vec) + chunk * 1024;
        const float4* h4 = reinterpret_cast<const float4*>(h) + chunk * 1024;
        float acc = 0.f;
        #pragma unroll
        for (int it = 0; it < 4; ++it) {
            float4 a = v4[it * 256 + tid];
            float4 hb = h4[it * 256 + tid];
            acc += a.x * hb.x + a.y * hb.y + a.z * hb.z + a.w * hb.w;
        }
        if (sd == 2 && chunk == 0) { // x-tail of u_content_alpha
            float4 a = reinterpret_cast<const float4*>(uca)[NN / 4 + tid];
            float4 xv = reinterpret_cast<const float4*>(x)[tid];
            acc += a.x * xv.x + a.y * xv.y + a.z * xv.z + a.w * xv.w;
        }
        #pragma unroll
        for (int off = 32; off >= 1; off >>= 1)
            acc += __shfl_xor(acc, off);
        if (lane == 0) red[wave][0] = acc;
        __syncthreads();
        if (tid == 0)
            atomicAdd(ws + 2112 + sd,
                      red[0][0] + red[1][0] + red[2][0] + red[3][0]);
    }
}

// ---------------- K1b: q bias, qnorm + scalar nonlinearities --------------
__global__ __launch_bounds__(256) void k1b_scalars(
    const float* __restrict__ bq, const float* __restrict__ bsh,
    const float* __restrict__ blr, const float* __restrict__ bca,
    float* __restrict__ ws)
{
    __shared__ float red[256];
    const int tid = threadIdx.x;
    float s = 0.f;
    for (int j = tid; j < 576; j += 256) {
        float q = ws[j] + bq[j];
        ws[QOFF + j] = q;
        s += q * q;
    }
    red[tid] = s; __syncthreads();
    for (int st = 128; st > 0; st >>= 1) {
        if (tid < st) red[tid] += red[tid + st];
        __syncthreads();
    }
    if (tid == 0) {
        float qn = fmaxf(sqrtf(red[0]), EPSV);
        float bp = ws[2112] + bsh[0];
        float beta = (bp > 20.f ? bp : log1pf(expf(bp))) + 1.0f;
        float gp = ws[2113] + blr[0];
        float gamma = 1.f / (1.f + expf(-gp));
        float alpha = ws[2114] + bca[0];
        ws[2112] = beta; ws[2113] = gamma; ws[2114] = alpha; ws[2115] = qn;
    }
}

// ---------------- K2: per-row norm + dot vs q -> logits s ------------------
// grid 2048 x 256 (4 waves), one wave per row, 4 rows per wave.
__global__ __launch_bounds__(256) void k2_sim(
    const float* __restrict__ Mm, const float* __restrict__ Ad,
    const float* __restrict__ ema, const float* __restrict__ ws,
    float* __restrict__ ws_s)
{
    const int tid = threadIdx.x, wave = tid >> 6, lane = tid & 63;
    const float beta = ws[2112], gamma = ws[2113], qn = ws[2115];
    const float ql = ws[QOFF + lane];
    float4 qa = *reinterpret_cast<const float4*>(ws + QOFF + 64 + lane * 8);
    float4 qb = *reinterpret_cast<const float4*>(ws + QOFF + 68 + lane * 8);
    float qm[8] = {qa.x, qa.y, qa.z, qa.w, qb.x, qb.y, qb.z, qb.w};
    #pragma unroll
    for (int j = 0; j < 4; ++j) {
        const int i = blockIdx.x * 16 + wave * 4 + j;
        float a = Ad[(size_t)i * AA + lane];
        float4 m0 = *reinterpret_cast<const float4*>(Mm + (size_t)i * CC + lane * 8);
        float4 m1 = *reinterpret_cast<const float4*>(Mm + (size_t)i * CC + lane * 8 + 4);
        float mm[8] = {m0.x, m0.y, m0.z, m0.w, m1.x, m1.y, m1.z, m1.w};
        float dot = a * ql, nn = a * a;
        #pragma unroll
        for (int k = 0; k < 8; ++k) { float f = mm[k]; dot += f * qm[k]; nn += f * f; }
        #pragma unroll
        for (int off = 32; off >= 1; off >>= 1) {
            dot += __shfl_xor(dot, off);
            nn  += __shfl_xor(nn, off);
        }
        if (lane == 0) {
            float mn = fmaxf(sqrtf(nn), EPSV);
            ws_s[i] = beta * (dot / (mn * qn)) - gamma * ema[i];
        }
    }
}

// ---------------- K3: softmax stats (max, 1/Z, S2=sum addr^2) -------------
__global__ __launch_bounds__(1024) void k3_softmax(float* __restrict__ ws)
{
    const float* s = ws + SOFF;
    __shared__ float lmx[16], lz[16], ls2[16], bc[1];
    const int tid = threadIdx.x, lane = tid & 63, wid = tid >> 6;
    float v[32];
    float mx = -1e30f;
    #pragma unroll
    for (int j = 0; j < 32; ++j) { v[j] = s[tid + 1024 * j]; mx = fmaxf(mx, v[j]); }
    #pragma unroll
    for (int off = 32; off >= 1; off >>= 1) mx = fmaxf(mx, __shfl_xor(mx, off));
    if (lane == 0) lmx[wid] = mx;
    __syncthreads();
    if (tid == 0) { float m = lmx[0]; for (int k = 1; k < 16; ++k) m = fmaxf(m, lmx[k]); bc[0] = m; }
    __syncthreads();
    mx = bc[0];
    float z = 0.f, s2 = 0.f;
    #pragma unroll
    for (int j = 0; j < 32; ++j) { float e = expf(v[j] - mx); z += e; s2 += e * e; }
    #pragma unroll
    for (int off = 32; off >= 1; off >>= 1) { z += __shfl_xor(z, off); s2 += __shfl_xor(s2, off); }
    if (lane == 0) { lz[wid] = z; ls2[wid] = s2; }
    __syncthreads();
    if (tid == 0) {
        float Z = 0.f, S = 0.f;
        for (int k = 0; k < 16; ++k) { Z += lz[k]; S += ls2[k]; }
        ws[2116] = mx; ws[2117] = 1.f / Z; ws[2118] = S / (Z * Z);
    }
}

// ---------------- K4: weighted column sums of M (w1, w1^2) + addresses ----
// grid 640: blocks [0,512) -> M part (64 rows each); [512,640) -> A part (256 rows each)
__global__ __launch_bounds__(256) void k4_acc(
    const float* __restrict__ Mm, const float* __restrict__ Ad,
    const float* __restrict__ ws, float* __restrict__ pm, float* __restrict__ pa)
{
    __shared__ float lds[4][1024];
    const int b = blockIdx.x, tid = threadIdx.x, wave = tid >> 6, lane = tid & 63;
    const float* s = ws + SOFF;
    const float mx = ws[2116], invZ = ws[2117];
    if (b < 512) {
        float a1[8] = {0,0,0,0,0,0,0,0};
        float a2[8] = {0,0,0,0,0,0,0,0};
        for (int j = 0; j < 16; ++j) {
            const int i = b * 64 + j * 4 + wave;
            float w1 = expf(s[i] - mx) * invZ;
            float w2 = w1 * w1;
            float4 m0 = *reinterpret_cast<const float4*>(Mm + (size_t)i * CC + lane * 8);
            float4 m1 = *reinterpret_cast<const float4*>(Mm + (size_t)i * CC + lane * 8 + 4);
            float mm[8] = {m0.x, m0.y, m0.z, m0.w, m1.x, m1.y, m1.z, m1.w};
            #pragma unroll
            for (int k = 0; k < 8; ++k) { float f = mm[k]; a1[k] += w1 * f; a2[k] += w2 * f; }
        }
        #pragma unroll
        for (int k = 0; k < 8; ++k) {
            lds[wave][lane * 8 + k] = a1[k];
            lds[wave][512 + lane * 8 + k] = a2[k];
        }
        __syncthreads();
        for (int e = tid; e < 1024; e += 256) {
            float v = lds[0][e] + lds[1][e] + lds[2][e] + lds[3][e];
            pm[(size_t)e * 512 + b] = v;
        }
    } else {
        const int bb = b - 512;
        float acc = 0.f;
        for (int j = 0; j < 64; ++j) {
            const int i = bb * 256 + j * 4 + wave;
            float w1 = expf(s[i] - mx) * invZ;
            acc += w1 * Ad[(size_t)i * AA + lane];
        }
        lds[wave][lane] = acc;
        __syncthreads();
        if (tid < 64) {
            float v = lds[0][tid] + lds[1][tid] + lds[2][tid] + lds[3][tid];
            pa[tid * 128 + bb] = v;
        }
    }
}

// ---------------- K5: reduce partials + epilogue --------------------------
// grid 576: block b<64 -> out[b] from pa; else c=b-64 -> out[64+c]
__global__ __launch_bounds__(256) void k5_final(
    const float* __restrict__ ws, const float* __restrict__ pm,
    const float* __restrict__ pa, const float* __restrict__ ber,
    float* __restrict__ out)
{
    __shared__ float red[256];
    const int b = blockIdx.x, tid = threadIdx.x;
    if (b < 64) {
        float v = (tid < 128) ? pa[b * 128 + tid] : 0.f;
        red[tid] = v; __syncthreads();
        for (int st = 128; st > 0; st >>= 1) {
            if (tid < st) red[tid] += red[tid + st];
            __syncthreads();
        }
        if (tid == 0) out[b] = red[0];
    } else {
        const int c = b - 64;
        float v1 = pm[(size_t)c * 512 + tid] + pm[(size_t)c * 512 + tid + 256];
        float v2 = pm[(size_t)(512 + c) * 512 + tid] + pm[(size_t)(512 + c) * 512 + tid + 256];
        red[tid] = v1; __syncthreads();
        for (int st = 128; st > 0; st >>= 1) {
            if (tid < st) red[tid] += red[tid + st];
            __syncthreads();
        }
        float s1 = red[0];
        __syncthreads();
        red[tid] = v2; __syncthreads();
        for (int st = 128; st > 0; st >>= 1) {
            if (tid < st) red[tid] += red[tid + st];
            __syncthreads();
        }
        if (tid == 0) {
            float s2v = red[0];
            float er = ws[576 + c] + ber[c];
            float ch = ws[1088 + c], cx = ws[1600 + c];
            float alpha = ws[2114], S2 = ws[2118];
            float cand = fmaxf(ch + alpha * cx, 0.f);
            out[64 + c] = s1 - er * s2v + S2 * cand;
        }
    }
}

extern "C" void kernel_launch(void* const* d_in, const int* in_sizes, int n_in,
                              void* d_out, int out_size, void* d_ws, size_t ws_size,
                              hipStream_t stream)
{
    const float* h   = (const float*)d_in[0];
    const float* x   = (const float*)d_in[1];
    const float* Mm  = (const float*)d_in[2];
    const float* Ad  = (const float*)d_in[3];
    const float* ema = (const float*)d_in[4];
    const float* Wq  = (const float*)d_in[5];
    const float* bq  = (const float*)d_in[6];
    const float* ush = (const float*)d_in[7];
    const float* bsh = (const float*)d_in[8];
    const float* ulr = (const float*)d_in[9];
    const float* blr = (const float*)d_in[10];
    const float* Wer = (const float*)d_in[11];
    const float* ber = (const float*)d_in[12];
    const float* Wch = (const float*)d_in[13];
    const float* Wci = (const float*)d_in[14];
    const float* uca = (const float*)d_in[15];
    const float* bca = (const float*)d_in[16];

    float* ws   = (float*)d_ws;
    float* ws_s = ws + SOFF;
    float* pm   = ws + PMOFF;
    float* pa   = ws + PAOFF;
    float* out  = (float*)d_out;

    // zero atomic-accumulation targets ws[0,2128)
    hipMemsetAsync(ws, 0, QOFF * sizeof(float), stream);

    hipLaunchKernelGGL(k1_gemv,    dim3(1688), dim3(256),  0, stream,
                       h, x, Wq, Wer, Wch, Wci, ush, ulr, uca, ws);
    hipLaunchKernelGGL(k1b_scalars, dim3(1),   dim3(256),  0, stream,
                       bq, bsh, blr, bca, ws);
    hipLaunchKernelGGL(k2_sim,     dim3(2048), dim3(256),  0, stream, Mm, Ad, ema, ws, ws_s);
    hipLaunchKernelGGL(k3_softmax, dim3(1),    dim3(1024), 0, stream, ws);
    hipLaunchKernelGGL(k4_acc,     dim3(640),  dim3(256),  0, stream, Mm, Ad, ws, pm, pa);
    hipLaunchKernelGGL(k5_final,   dim3(576),  dim3(256),  0, stream, ws, pm, pa, ber, out);
}

// Round 5
// 280.979 us; speedup vs baseline: 1.1752x; 1.1752x over previous
//
#include <hip/hip_runtime.h>
#include <hip/hip_bf16.h>
#include <math.h>

// Problem constants
#define NN 32768
#define CC 512
#define AA 64
#define CIN 1024
#define EPSV 1e-7f

// All inputs/outputs are FLOAT32 (reference dtype).
//
// Workspace layout (floats):
//   [0,576)      query dots (atomic-accumulated, pre-bias)
//   [576,1088)   erase dots (pre-bias)
//   [1088,1600)  conth = W_content_hidden @ h
//   [1600,2112)  contx = W_content_input @ x   (direct store)
//   [2112,2128)  scalars: 2112 beta, 2113 gamma, 2114 alpha, 2115 qnorm,
//                         2118 S2_global
//   [2128,2704)  qfull[576] = query + b_query
//   [2704,4240)  stats[1536]: m_b[512], Zl[512], S2l[512]
//   [4240,5264)  sc[1024]: sc1[512], sc2[512]
//   [5264,38032) pa[64][512]   (A-col partials, col-major: j*512+b)
//   [38032,562320) pm[1024][512] (M-col partials: e*512+b; e<512 -> w*M, e>=512 -> w^2*M)
// Total 562320 floats = 2.25 MB

#define QOFF 2128
#define STOFF 2704
#define SCOFF 4240
#define PAOFF 5264
#define PMOFF 38032

typedef float floatx4 __attribute__((ext_vector_type(4)));

__device__ __forceinline__ float4 ntload4(const float4* p) {
    floatx4 v = __builtin_nontemporal_load(reinterpret_cast<const floatx4*>(p));
    return make_float4(v.x, v.y, v.z, v.w);
}
__device__ __forceinline__ float ntloadf(const float* p) {
    return __builtin_nontemporal_load(p);
}

// ---------------- K1: all GEMVs + scalar dots, row-blocked ----------------
// grid 1688 blocks x 256 thr:
//   b<1600 : big GEMV (rows [0,1600) over Wq/Wer/Wch). rg=b>>3 (8 rows),
//            chunk=b&7 (4096 cols). h chunk staged in LDS, shared by 8 rows.
//            Register double-buffer across the 4 col-iterations; nt loads.
//   b<1664 : Wci rows (8 per block, full 1024 cols) -> direct store.
//   b<1688 : 3 scalar dots x 8 chunks -> atomicAdd(ws[2112+sd]).
__global__ __launch_bounds__(256) void k1_gemv(
    const float* __restrict__ h, const float* __restrict__ x,
    const float* __restrict__ Wq, const float* __restrict__ Wer,
    const float* __restrict__ Wch, const float* __restrict__ Wci,
    const float* __restrict__ ush, const float* __restrict__ ulr,
    const float* __restrict__ uca, float* __restrict__ ws)
{
    const int b = blockIdx.x, tid = threadIdx.x;
    const int wave = tid >> 6, lane = tid & 63;
    __shared__ float hs[4096];
    __shared__ float red[4][8];

    if (b < 1600) {
        const int rg = b >> 3, chunk = b & 7;
        const float4* h4 = reinterpret_cast<const float4*>(h) + chunk * 1024;
        float4* hs4 = reinterpret_cast<float4*>(hs);
        #pragma unroll
        for (int k = 0; k < 4; ++k) hs4[k * 256 + tid] = h4[k * 256 + tid];
        __syncthreads();
        const int r0 = rg * 8;
        const float* mat; int base;
        if (r0 < 576)       { mat = Wq;  base = 0; }
        else if (r0 < 1088) { mat = Wer; base = 576; }
        else                { mat = Wch; base = 1088; }
        const float4* m4 = reinterpret_cast<const float4*>(
            mat + (size_t)(r0 - base) * NN + chunk * 4096);
        const int rs = NN / 4; // row stride in float4
        float acc[8] = {0,0,0,0,0,0,0,0};
        float4 cur[8];
        #pragma unroll
        for (int r = 0; r < 8; ++r) cur[r] = ntload4(m4 + (size_t)r * rs + tid);
        #pragma unroll
        for (int it = 0; it < 4; ++it) {
            float4 nxt[8];
            if (it < 3) {
                #pragma unroll
                for (int r = 0; r < 8; ++r)
                    nxt[r] = ntload4(m4 + (size_t)r * rs + (it + 1) * 256 + tid);
            }
            float4 hb = hs4[it * 256 + tid];
            #pragma unroll
            for (int r = 0; r < 8; ++r)
                acc[r] += cur[r].x * hb.x + cur[r].y * hb.y +
                          cur[r].z * hb.z + cur[r].w * hb.w;
            if (it < 3) {
                #pragma unroll
                for (int r = 0; r < 8; ++r) cur[r] = nxt[r];
            }
        }
        #pragma unroll
        for (int r = 0; r < 8; ++r) {
            #pragma unroll
            for (int off = 32; off >= 1; off >>= 1)
                acc[r] += __shfl_xor(acc[r], off);
        }
        if (lane == 0) {
            #pragma unroll
            for (int r = 0; r < 8; ++r) red[wave][r] = acc[r];
        }
        __syncthreads();
        if (tid < 8) {
            float v = red[0][tid] + red[1][tid] + red[2][tid] + red[3][tid];
            atomicAdd(ws + r0 + tid, v);
        }
    } else if (b < 1664) {
        const int rg = b - 1600; // 8 rows of Wci each
        float4 xv = reinterpret_cast<const float4*>(x)[tid];
        const float4* m4 = reinterpret_cast<const float4*>(
            Wci + (size_t)rg * 8 * CIN);
        float acc[8];
        #pragma unroll
        for (int r = 0; r < 8; ++r) {
            float4 a = ntload4(m4 + r * 256 + tid);
            acc[r] = a.x * xv.x + a.y * xv.y + a.z * xv.z + a.w * xv.w;
        }
        #pragma unroll
        for (int r = 0; r < 8; ++r) {
            #pragma unroll
            for (int off = 32; off >= 1; off >>= 1)
                acc[r] += __shfl_xor(acc[r], off);
        }
        if (lane == 0) {
            #pragma unroll
            for (int r = 0; r < 8; ++r) red[wave][r] = acc[r];
        }
        __syncthreads();
        if (tid < 8) {
            float v = red[0][tid] + red[1][tid] + red[2][tid] + red[3][tid];
            ws[1600 + rg * 8 + tid] = v;
        }
    } else {
        const int t = b - 1664, sd = t >> 3, chunk = t & 7;
        const float* vec = (sd == 0) ? ush : (sd == 1) ? ulr : uca;
        const float4* v4 = reinterpret_cast<const float4*>(vec) + chunk * 1024;
        const float4* h4 = reinterpret_cast<const float4*>(h) + chunk * 1024;
        float acc = 0.f;
        #pragma unroll
        for (int it = 0; it < 4; ++it) {
            float4 a = v4[it * 256 + tid];
            float4 hb = h4[it * 256 + tid];
            acc += a.x * hb.x + a.y * hb.y + a.z * hb.z + a.w * hb.w;
        }
        if (sd == 2 && chunk == 0) { // x-tail of u_content_alpha
            float4 a = reinterpret_cast<const float4*>(uca)[NN / 4 + tid];
            float4 xv = reinterpret_cast<const float4*>(x)[tid];
            acc += a.x * xv.x + a.y * xv.y + a.z * xv.z + a.w * xv.w;
        }
        #pragma unroll
        for (int off = 32; off >= 1; off >>= 1)
            acc += __shfl_xor(acc, off);
        if (lane == 0) red[wave][0] = acc;
        __syncthreads();
        if (tid == 0)
            atomicAdd(ws + 2112 + sd,
                      red[0][0] + red[1][0] + red[2][0] + red[3][0]);
    }
}

// ---------------- K1b: q bias, qnorm + scalar nonlinearities --------------
__global__ __launch_bounds__(256) void k1b_scalars(
    const float* __restrict__ bq, const float* __restrict__ bsh,
    const float* __restrict__ blr, const float* __restrict__ bca,
    float* __restrict__ ws)
{
    __shared__ float red[256];
    const int tid = threadIdx.x;
    float s = 0.f;
    for (int j = tid; j < 576; j += 256) {
        float q = ws[j] + bq[j];
        ws[QOFF + j] = q;
        s += q * q;
    }
    red[tid] = s; __syncthreads();
    for (int st = 128; st > 0; st >>= 1) {
        if (tid < st) red[tid] += red[tid + st];
        __syncthreads();
    }
    if (tid == 0) {
        float qn = fmaxf(sqrtf(red[0]), EPSV);
        float bp = ws[2112] + bsh[0];
        float beta = (bp > 20.f ? bp : log1pf(expf(bp))) + 1.0f;
        float gp = ws[2113] + blr[0];
        float gamma = 1.f / (1.f + expf(-gp));
        float alpha = ws[2114] + bca[0];
        ws[2112] = beta; ws[2113] = gamma; ws[2114] = alpha; ws[2115] = qn;
    }
}

// ---------------- K2f: fused sim + online-softmax + weighted accumulation -
// grid 512 x 512 (8 waves). Block b handles rows [b*64, b*64+64); wave w
// handles 8 rows. Single pass over M+A: per row compute logit s_i, then
// online-softmax accumulate  a1 += w*M_row, a2 += w^2*M_row, aA += w*A_row,
// Z += w, S2 += w^2  with running-max rescaling. Block merge in LDS with
// per-wave scale factors; emit per-block partials + (m_b, Zl, S2l) stats.
__global__ __launch_bounds__(512) void k2f_fused(
    const float* __restrict__ Mm, const float* __restrict__ Ad,
    const float* __restrict__ ema, const float* __restrict__ ws,
    float* __restrict__ pm, float* __restrict__ pa, float* __restrict__ stats)
{
    __shared__ float lw[8][1092];
    const int b = blockIdx.x, tid = threadIdx.x, wave = tid >> 6, lane = tid & 63;
    const float beta = ws[2112], gamma = ws[2113], qn = ws[2115];
    const float ql = ws[QOFF + lane];
    float4 qa = *reinterpret_cast<const float4*>(ws + QOFF + 64 + lane * 8);
    float4 qb = *reinterpret_cast<const float4*>(ws + QOFF + 68 + lane * 8);
    float qm[8] = {qa.x, qa.y, qa.z, qa.w, qb.x, qb.y, qb.z, qb.w};

    float a1[8] = {0,0,0,0,0,0,0,0};
    float a2[8] = {0,0,0,0,0,0,0,0};
    float aA = 0.f, m_run = -1e30f, Z = 0.f, S2 = 0.f;
    const int base = b * 64 + wave * 8;
    for (int j = 0; j < 8; ++j) {
        const int i = base + j;
        float a = ntloadf(Ad + (size_t)i * AA + lane);
        float4 m0 = ntload4(reinterpret_cast<const float4*>(Mm + (size_t)i * CC + lane * 8));
        float4 m1 = ntload4(reinterpret_cast<const float4*>(Mm + (size_t)i * CC + lane * 8 + 4));
        float mm[8] = {m0.x, m0.y, m0.z, m0.w, m1.x, m1.y, m1.z, m1.w};
        float dot = a * ql, nn = a * a;
        #pragma unroll
        for (int k = 0; k < 8; ++k) { float f = mm[k]; dot += f * qm[k]; nn += f * f; }
        #pragma unroll
        for (int off = 32; off >= 1; off >>= 1) {
            dot += __shfl_xor(dot, off);
            nn  += __shfl_xor(nn, off);
        }
        float mn = fmaxf(sqrtf(nn), EPSV);
        float s = beta * (dot / (mn * qn)) - gamma * ema[i];
        if (s > m_run) {                  // wave-uniform branch
            float f = expf(m_run - s);    // 0 on first row (exp(-huge))
            float f2 = f * f;
            Z *= f; S2 *= f2; aA *= f;
            #pragma unroll
            for (int k = 0; k < 8; ++k) { a1[k] *= f; a2[k] *= f2; }
            m_run = s;
        }
        float w = expf(s - m_run);
        float w2 = w * w;
        Z += w; S2 += w2; aA += w * a;
        #pragma unroll
        for (int k = 0; k < 8; ++k) { a1[k] += w * mm[k]; a2[k] += w2 * mm[k]; }
    }
    // wave partials -> LDS
    #pragma unroll
    for (int k = 0; k < 8; ++k) {
        lw[wave][lane * 8 + k] = a1[k];
        lw[wave][512 + lane * 8 + k] = a2[k];
    }
    lw[wave][1024 + lane] = aA;
    if (lane == 0) { lw[wave][1088] = m_run; lw[wave][1089] = Z; lw[wave][1090] = S2; }
    __syncthreads();
    // block merge with per-wave rescale
    float mb = lw[0][1088];
    #pragma unroll
    for (int w = 1; w < 8; ++w) mb = fmaxf(mb, lw[w][1088]);
    float fw[8];
    #pragma unroll
    for (int w = 0; w < 8; ++w) fw[w] = expf(lw[w][1088] - mb);
    for (int e = tid; e < 1024; e += 512) {
        float v = 0.f;
        if (e < 512) {
            #pragma unroll
            for (int w = 0; w < 8; ++w) v += fw[w] * lw[w][e];
        } else {
            #pragma unroll
            for (int w = 0; w < 8; ++w) v += fw[w] * fw[w] * lw[w][e];
        }
        pm[(size_t)e * 512 + b] = v;
    }
    if (tid < 64) {
        float v = 0.f;
        #pragma unroll
        for (int w = 0; w < 8; ++w) v += fw[w] * lw[w][1024 + tid];
        pa[tid * 512 + b] = v;
    }
    if (tid == 0) {
        float Zl = 0.f, S2l = 0.f;
        #pragma unroll
        for (int w = 0; w < 8; ++w) {
            Zl  += fw[w] * lw[w][1089];
            S2l += fw[w] * fw[w] * lw[w][1090];
        }
        stats[b] = mb; stats[512 + b] = Zl; stats[1024 + b] = S2l;
    }
}

// ---------------- K3g: global softmax stats + per-block scale factors -----
__global__ __launch_bounds__(512) void k3g(
    const float* __restrict__ stats, float* __restrict__ sc,
    float* __restrict__ ws)
{
    __shared__ float red[512];
    const int t = threadIdx.x;
    float m = stats[t];
    red[t] = m; __syncthreads();
    for (int st = 256; st > 0; st >>= 1) {
        if (t < st) red[t] = fmaxf(red[t], red[t + st]);
        __syncthreads();
    }
    float mx = red[0]; __syncthreads();
    float e1 = expf(m - mx);
    red[t] = e1 * stats[512 + t]; __syncthreads();
    for (int st = 256; st > 0; st >>= 1) {
        if (t < st) red[t] += red[t + st];
        __syncthreads();
    }
    float Zg = red[0]; __syncthreads();
    red[t] = e1 * e1 * stats[1024 + t]; __syncthreads();
    for (int st = 256; st > 0; st >>= 1) {
        if (t < st) red[t] += red[t + st];
        __syncthreads();
    }
    float S2s = red[0];
    float iZ = 1.f / Zg;
    sc[t] = e1 * iZ;
    sc[512 + t] = e1 * e1 * iZ * iZ;
    if (t == 0) ws[2118] = S2s * iZ * iZ;
}

// ---------------- K5: reduce partials + epilogue --------------------------
// grid 576: block b<64 -> out[b] from pa; else c=b-64 -> out[64+c]
__global__ __launch_bounds__(256) void k5_final(
    const float* __restrict__ ws, const float* __restrict__ pm,
    const float* __restrict__ pa, const float* __restrict__ sc,
    const float* __restrict__ ber, float* __restrict__ out)
{
    __shared__ float red[256];
    const int b = blockIdx.x, tid = threadIdx.x;
    if (b < 64) {
        float v = sc[tid] * pa[b * 512 + tid] + sc[tid + 256] * pa[b * 512 + tid + 256];
        red[tid] = v; __syncthreads();
        for (int st = 128; st > 0; st >>= 1) {
            if (tid < st) red[tid] += red[tid + st];
            __syncthreads();
        }
        if (tid == 0) out[b] = red[0];
    } else {
        const int c = b - 64;
        float v1 = sc[tid] * pm[(size_t)c * 512 + tid]
                 + sc[tid + 256] * pm[(size_t)c * 512 + tid + 256];
        float v2 = sc[512 + tid] * pm[(size_t)(512 + c) * 512 + tid]
                 + sc[512 + tid + 256] * pm[(size_t)(512 + c) * 512 + tid + 256];
        red[tid] = v1; __syncthreads();
        for (int st = 128; st > 0; st >>= 1) {
            if (tid < st) red[tid] += red[tid + st];
            __syncthreads();
        }
        float s1 = red[0];
        __syncthreads();
        red[tid] = v2; __syncthreads();
        for (int st = 128; st > 0; st >>= 1) {
            if (tid < st) red[tid] += red[tid + st];
            __syncthreads();
        }
        if (tid == 0) {
            float s2v = red[0];
            float er = ws[576 + c] + ber[c];
            float ch = ws[1088 + c], cx = ws[1600 + c];
            float alpha = ws[2114], S2 = ws[2118];
            float cand = fmaxf(ch + alpha * cx, 0.f);
            out[64 + c] = s1 - er * s2v + S2 * cand;
        }
    }
}

extern "C" void kernel_launch(void* const* d_in, const int* in_sizes, int n_in,
                              void* d_out, int out_size, void* d_ws, size_t ws_size,
                              hipStream_t stream)
{
    const float* h   = (const float*)d_in[0];
    const float* x   = (const float*)d_in[1];
    const float* Mm  = (const float*)d_in[2];
    const float* Ad  = (const float*)d_in[3];
    const float* ema = (const float*)d_in[4];
    const float* Wq  = (const float*)d_in[5];
    const float* bq  = (const float*)d_in[6];
    const float* ush = (const float*)d_in[7];
    const float* bsh = (const float*)d_in[8];
    const float* ulr = (const float*)d_in[9];
    const float* blr = (const float*)d_in[10];
    const float* Wer = (const float*)d_in[11];
    const float* ber = (const float*)d_in[12];
    const float* Wch = (const float*)d_in[13];
    const float* Wci = (const float*)d_in[14];
    const float* uca = (const float*)d_in[15];
    const float* bca = (const float*)d_in[16];

    float* ws    = (float*)d_ws;
    float* stats = ws + STOFF;
    float* sc    = ws + SCOFF;
    float* pa    = ws + PAOFF;
    float* pm    = ws + PMOFF;
    float* out   = (float*)d_out;

    // zero atomic-accumulation targets ws[0,2128)
    (void)hipMemsetAsync(ws, 0, QOFF * sizeof(float), stream);

    hipLaunchKernelGGL(k1_gemv,     dim3(1688), dim3(256), 0, stream,
                       h, x, Wq, Wer, Wch, Wci, ush, ulr, uca, ws);
    hipLaunchKernelGGL(k1b_scalars, dim3(1),    dim3(256), 0, stream,
                       bq, bsh, blr, bca, ws);
    hipLaunchKernelGGL(k2f_fused,   dim3(512),  dim3(512), 0, stream,
                       Mm, Ad, ema, ws, pm, pa, stats);
    hipLaunchKernelGGL(k3g,         dim3(1),    dim3(512), 0, stream, stats, sc, ws);
    hipLaunchKernelGGL(k5_final,    dim3(576),  dim3(256), 0, stream,
                       ws, pm, pa, sc, ber, out);
}